// Round 7
// baseline (462.961 us; speedup 1.0000x reference)
//
#include <hip/hip_runtime.h>

#define LVLS  16
#define TSZ   524288u          // 2^19
#define TMASK (TSZ - 1u)
#define PRIME 2654435761u

// floor(16 * g^l), g = 128^(1/15) — matches np float64 floor then f32 cast
__constant__ float RES[LVLS] = {16.f, 22.f, 30.f, 42.f, 58.f, 80.f, 111.f, 153.f,
                                212.f, 294.f, 406.f, 561.f, 776.f, 1072.f, 1482.f, 2048.f};

typedef __bf16 bf16x8 __attribute__((ext_vector_type(8)));
typedef float  f32x4  __attribute__((ext_vector_type(4)));

union Frag {
    uint4          q;
    unsigned       u[4];
    unsigned short s[8];
    bf16x8         v;
};

static __device__ __forceinline__ unsigned short f2bf(float f) {
    unsigned u = __float_as_uint(f);
    u += 0x7FFFu + ((u >> 16) & 1u);          // RNE; inputs finite, non-NaN
    return (unsigned short)(u >> 16);
}
static __device__ __forceinline__ unsigned pack2(float a, float b) {
    unsigned ua = __float_as_uint(a), ub = __float_as_uint(b);
    ua += 0x7FFFu + ((ua >> 16) & 1u);
    ub += 0x7FFFu + ((ub >> 16) & 1u);
    return (ua >> 16) | (ub & 0xFFFF0000u);
}
static __device__ __forceinline__ void lds_fence() {
    asm volatile("s_waitcnt lgkmcnt(0)" ::: "memory");
}

// ============ precompute MLP B-operand fragments (bf16) into ws ============
// B layout: lane holds col n=lane&15, k=quad*8+j. Hidden-unit storage slot
// eta = 4c+t (ReLU writes pack into b64); W1/W2 rows remapped:
// orig = (eta&3)*16 + (eta>>2).
__global__ __launch_bounds__(256) void k_frag(
    const float* __restrict__ W0, const float* __restrict__ W1,
    const float* __restrict__ W2, uint4* __restrict__ frg)
{
    const int lane = threadIdx.x & 63;
    const int wv   = threadIdx.x >> 6;
    const int c = lane & 15, quad = lane >> 4;
    for (int set = wv; set < 14; set += 4) {
        Frag t;
        if (set < 4) {
            const int f = set;
            #pragma unroll
            for (int j = 0; j < 8; ++j)
                t.s[j] = f2bf(W0[(quad * 8 + j) * 64 + f * 16 + c]);
        } else if (set < 12) {
            const int ff = set - 4;
            const int kt = ff >> 2, tt = ff & 3;
            #pragma unroll
            for (int j = 0; j < 8; ++j) {
                const int eta = kt * 32 + quad * 8 + j;
                const int orig = (eta & 3) * 16 + (eta >> 2);
                t.s[j] = f2bf(W1[orig * 64 + tt * 16 + c]);
            }
        } else {
            const int f = set - 12;
            #pragma unroll
            for (int j = 0; j < 8; ++j) {
                const int eta = f * 32 + quad * 8 + j;
                const int orig = (eta & 3) * 16 + (eta >> 2);
                const float v = (c < 3) ? W2[orig * 3 + c] : 0.f;
                t.s[j] = f2bf(v);
            }
        }
        frg[set * 64 + lane] = t.q;
    }
}

// ============ fused encode + MLP ============
// One wave = 16 points/tile. Lane quad*16+c owns point n0+c, levels
// quad*4..quad*4+3 — gathers its 16 corners and packs its A0 fragment
// directly in registers (A[m=lane&15][k=quad*8+j], feature k = level
// quad*4 + (j>>1), component j&1). MLP: verified B-frag/hscr pipeline.
#define TPW 4   // tiles per wave
__global__ __launch_bounds__(256, 4) void ngp_fused(
    const float2* __restrict__ x, const float* __restrict__ tables,
    const uint4* __restrict__ frg,
    const float* __restrict__ b0, const float* __restrict__ b1,
    const float* __restrict__ b2, float* __restrict__ out, int N)
{
    __shared__ __align__(16) unsigned short hscr[4][16][72];

    const int tid  = threadIdx.x;
    const int lane = tid & 63;
    const int w    = tid >> 6;
    const int c    = lane & 15;
    const int quad = lane >> 4;

    Frag B0f[4], B1f[8], B2f[2];
    #pragma unroll
    for (int t = 0; t < 4; ++t) B0f[t].q = frg[t * 64 + lane];
    #pragma unroll
    for (int f = 0; f < 8; ++f) B1f[f].q = frg[(4 + f) * 64 + lane];
    #pragma unroll
    for (int f = 0; f < 2; ++f) B2f[f].q = frg[(12 + f) * 64 + lane];

    float bias0[4], bias1[4];
    #pragma unroll
    for (int t = 0; t < 4; ++t) { bias0[t] = b0[t * 16 + c]; bias1[t] = b1[t * 16 + c]; }
    const float bias2 = (c < 3) ? b2[c] : 0.f;

    const int nTiles = N >> 4;
    int tile = (blockIdx.x * 4 + w) * TPW;

    #pragma unroll 1
    for (int it = 0; it < TPW; ++it, ++tile) {
        if (tile >= nTiles) break;
        const int n0 = tile * 16;

        // ---- encode: gather 16 corners (2 batches of 8), pack A0 ----
        const float2 xy = x[n0 + c];
        Frag a0;
        #pragma unroll
        for (int pr = 0; pr < 2; ++pr) {
            unsigned idx[8];
            float uxa[2], uya[2];
            #pragma unroll
            for (int j = 0; j < 2; ++j) {
                const int l = quad * 4 + 2 * pr + j;
                const float r = RES[l];
                const float sx = xy.x * r, sy = xy.y * r;
                const float fx = floorf(sx), fy = floorf(sy);
                uxa[j] = sx - fx; uya[j] = sy - fy;
                const unsigned ix = (unsigned)(int)fx, iy = (unsigned)(int)fy;
                const unsigned hy0 = iy * PRIME, hy1 = (iy + 1u) * PRIME;
                idx[4 * j + 0] = (ix ^ hy0) & TMASK;
                idx[4 * j + 1] = ((ix + 1u) ^ hy0) & TMASK;
                idx[4 * j + 2] = (ix ^ hy1) & TMASK;
                idx[4 * j + 3] = ((ix + 1u) ^ hy1) & TMASK;
            }
            float2 f[8];
            #pragma unroll
            for (int j = 0; j < 2; ++j) {
                const int l = quad * 4 + 2 * pr + j;
                const float2* tb = (const float2*)(tables + (size_t)l * (TSZ * 2));
                f[4 * j + 0] = tb[idx[4 * j + 0]];
                f[4 * j + 1] = tb[idx[4 * j + 1]];
                f[4 * j + 2] = tb[idx[4 * j + 2]];
                f[4 * j + 3] = tb[idx[4 * j + 3]];
            }
            #pragma unroll
            for (int j = 0; j < 2; ++j) {
                const float w00 = (1.f - uxa[j]) * (1.f - uya[j]);
                const float w10 = uxa[j] * (1.f - uya[j]);
                const float w01 = (1.f - uxa[j]) * uya[j];
                const float w11 = uxa[j] * uya[j];
                const float e0 = w00 * f[4*j+0].x + w10 * f[4*j+1].x + w01 * f[4*j+2].x + w11 * f[4*j+3].x;
                const float e1 = w00 * f[4*j+0].y + w10 * f[4*j+1].y + w01 * f[4*j+2].y + w11 * f[4*j+3].y;
                a0.u[2 * pr + j] = pack2(e0, e1);
            }
        }

        // ---- layer 0: 32 -> 64 ----
        f32x4 acc[4];
        #pragma unroll
        for (int t = 0; t < 4; ++t) {
            f32x4 cin = {bias0[t], bias0[t], bias0[t], bias0[t]};
            acc[t] = __builtin_amdgcn_mfma_f32_16x16x32_bf16(a0.v, B0f[t].v, cin, 0, 0, 0);
        }

        // relu -> LDS (slot eta=4c+t -> one b64 per row)
        lds_fence();
        #pragma unroll
        for (int rr = 0; rr < 4; ++rr) {
            uint2 pk;
            pk.x = pack2(fmaxf(acc[0][rr], 0.f), fmaxf(acc[1][rr], 0.f));
            pk.y = pack2(fmaxf(acc[2][rr], 0.f), fmaxf(acc[3][rr], 0.f));
            *(uint2*)&hscr[w][quad * 4 + rr][4 * c] = pk;
        }
        lds_fence();
        Frag a1[2];
        #pragma unroll
        for (int kt = 0; kt < 2; ++kt)
            a1[kt].q = *(const uint4*)&hscr[w][c][kt * 32 + quad * 8];

        // ---- layer 1: 64 -> 64 ----
        #pragma unroll
        for (int t = 0; t < 4; ++t) {
            f32x4 cin = {bias1[t], bias1[t], bias1[t], bias1[t]};
            cin = __builtin_amdgcn_mfma_f32_16x16x32_bf16(a1[0].v, B1f[t].v, cin, 0, 0, 0);
            acc[t] = __builtin_amdgcn_mfma_f32_16x16x32_bf16(a1[1].v, B1f[4 + t].v, cin, 0, 0, 0);
        }

        lds_fence();
        #pragma unroll
        for (int rr = 0; rr < 4; ++rr) {
            uint2 pk;
            pk.x = pack2(fmaxf(acc[0][rr], 0.f), fmaxf(acc[1][rr], 0.f));
            pk.y = pack2(fmaxf(acc[2][rr], 0.f), fmaxf(acc[3][rr], 0.f));
            *(uint2*)&hscr[w][quad * 4 + rr][4 * c] = pk;
        }
        lds_fence();
        Frag a2[2];
        #pragma unroll
        for (int kt = 0; kt < 2; ++kt)
            a2[kt].q = *(const uint4*)&hscr[w][c][kt * 32 + quad * 8];

        // ---- layer 2: 64 -> 3 + sigmoid + store ----
        f32x4 cin2 = {bias2, bias2, bias2, bias2};
        cin2 = __builtin_amdgcn_mfma_f32_16x16x32_bf16(a2[0].v, B2f[0].v, cin2, 0, 0, 0);
        const f32x4 o = __builtin_amdgcn_mfma_f32_16x16x32_bf16(a2[1].v, B2f[1].v, cin2, 0, 0, 0);
        if (c < 3) {
            #pragma unroll
            for (int rr = 0; rr < 4; ++rr) {
                const float sg = 1.f / (1.f + __expf(-o[rr]));
                out[(size_t)(n0 + quad * 4 + rr) * 3 + c] = sg;
            }
        }
    }
}

extern "C" void kernel_launch(void* const* d_in, const int* in_sizes, int n_in,
                              void* d_out, int out_size, void* d_ws, size_t ws_size,
                              hipStream_t stream) {
    const float* x      = (const float*)d_in[0];
    const float* tables = (const float*)d_in[1];
    const float* W0     = (const float*)d_in[2];
    const float* b0     = (const float*)d_in[3];
    const float* W1     = (const float*)d_in[4];
    const float* b1     = (const float*)d_in[5];
    const float* W2     = (const float*)d_in[6];
    const float* b2     = (const float*)d_in[7];
    float* out = (float*)d_out;

    const int N = in_sizes[0] / 2;
    uint4* frg = (uint4*)d_ws;                 // 14*64*16 B

    k_frag<<<1, 256, 0, stream>>>(W0, W1, W2, frg);

    const int nTiles = N >> 4;
    const int blocks = (nTiles + 4 * TPW - 1) / (4 * TPW);
    ngp_fused<<<blocks, 256, 0, stream>>>((const float2*)x, tables, frg,
                                          b0, b1, b2, out, N);
}